// Round 17
// baseline (687.921 us; speedup 1.0000x reference)
//
#include <hip/hip_runtime.h>
#include <float.h>

#define DECAY 0.1f
#define OMD   0.9f
#define EPS   1e-5f
#define NORM_EPS 1e-8f

static constexpr int D = 32;

typedef __attribute__((ext_vector_type(8))) short s16x8;
typedef __attribute__((ext_vector_type(4))) float f32x4_t;

__device__ __forceinline__ float bf2f(short s) {
    return __uint_as_float(((unsigned int)(unsigned short)s) << 16);
}

struct Split3 { short b0, b1, b2; };

// Exact 3-way bf16 truncation split: v == b0 + b1 + b2 (fp32 mantissa = 24 bits = 3x8).
__device__ __forceinline__ Split3 split3(float v) {
    const unsigned int u0 = __float_as_uint(v) & 0xFFFF0000u;
    const float r  = v - __uint_as_float(u0);
    const unsigned int u1 = __float_as_uint(r) & 0xFFFF0000u;
    const float r2 = r - __uint_as_float(u1);
    Split3 s;
    s.b0 = (short)(u0 >> 16);
    s.b1 = (short)(u1 >> 16);
    s.b2 = (short)(__float_as_uint(r2) >> 16);
    return s;
}

// ---------------- K1: normalize codebook + pack MFMA B-tiles + seed o_avg ---
// Per 16-code tile (3136 B global): 3 planes x 1024 B of bf16 B-fragments, then
// 16 floats of -|en|^2 (64 B). B[k][col] = 2*en[tile*16+col][k]; lane l holds
// k-chunk l>>4, col l&15. Also seeds o_avg row k = embed_avg_k * DECAY.
__global__ void prep_codebook(const float* __restrict__ embed,
                              const float* __restrict__ embed_avg,
                              unsigned short* __restrict__ bfrag,
                              float* __restrict__ o_avg,
                              int K) {
    const int k = blockIdx.x * blockDim.x + threadIdx.x;
    if (k >= K) return;
    float v[D]; float ssq = 0.f;
#pragma unroll
    for (int d = 0; d < D; ++d) { v[d] = embed[(size_t)k * D + d]; ssq += v[d] * v[d]; }
    const float inv = 1.0f / (sqrtf(ssq) + NORM_EPS);
    float e2 = 0.f;
    short p0[D], p1[D], p2[D];
#pragma unroll
    for (int d = 0; d < D; ++d) {
        const float e = v[d] * inv;
        e2 += e * e;
        const Split3 s = split3(2.0f * e);   // fold the *2 into the splits (exact)
        p0[d] = s.b0; p1[d] = s.b1; p2[d] = s.b2;
    }
    char* base = (char*)bfrag + (size_t)(k >> 4) * 3136;   // tile base, bytes
    const int col = k & 15;
    *(float*)(base + 3072 + col * 4) = -e2;
#pragma unroll
    for (int g = 0; g < 4; ++g) {                 // k-chunk g -> lane g*16+col
        const int lid = g * 16 + col;
        s16x8 s0, s1, s2;
#pragma unroll
        for (int i = 0; i < 8; ++i) { s0[i] = p0[g*8+i]; s1[i] = p1[g*8+i]; s2[i] = p2[g*8+i]; }
        *(s16x8*)(base +    0 + lid * 16) = s0;
        *(s16x8*)(base + 1024 + lid * 16) = s1;
        *(s16x8*)(base + 2048 + lid * 16) = s2;
    }
#pragma unroll
    for (int d = 0; d < D; ++d)
        o_avg[(size_t)k * D + d] = embed_avg[(size_t)k * D + d] * DECAY;
}

// B tile held entirely in registers (13 VGPRs).
struct Btile { s16x8 b0, b1, b2; float ne2; };

// ---------------- K2: MFMA assignment + fused last-block scatter ------------
// 512 thr = 8 waves, 256 points/block, grid = (N/256)*8 = 2048. Block handles
// ONE team's code range (K/8 = 512 codes = 32 tiles) for 256 points; all 8
// waves stream the SAME tiles in convoy -> 7/8 of B-loads are L1 hits.
// Cross-team argmax: packed-u64 atomicMax (ordered score | ~code) -- exact
// first-max / lowest-code. The LAST of the 8 team-blocks for a point range
// (device-scope atomic counter) performs the scatter for its 256 points,
// overlapped with other blocks' ongoing K-loops (R16's separate scatter
// kernel cost ~60us serial; fused it hides).
__global__ __launch_bounds__(512)
void assign_kernel(const float* __restrict__ x,
                   const unsigned short* __restrict__ bfrag,
                   unsigned long long* __restrict__ packed,
                   unsigned int* __restrict__ cnt,
                   float* __restrict__ out_quant,
                   float* __restrict__ out_ind,
                   float* __restrict__ bins,
                   float* __restrict__ o_avg,
                   int N, int K) {
    __shared__ char sm[49152];           // 8 waves x 6144 B A-fragment exchange
    __shared__ int  lastflag;

    const int tid  = threadIdx.x;
    const int lane = tid & 63;
    const int w    = tid >> 6;
    const int bid  = blockIdx.x;
    const int team = bid & 7;
    const int n0   = (bid >> 3) * 256;   // block's first point
    const int col  = lane & 15;
    char* wbase = &sm[w * 6144];

    // ---- phase 1: per-wave 32 points, 2 lanes/pt x 16 floats ----
    {
        const int pw = lane >> 1, h = lane & 1;
        const float* xp = &x[(size_t)(n0 + w * 32 + pw) * D + h * 16];
        const float4 va = *(const float4*)(xp);
        const float4 vb = *(const float4*)(xp + 4);
        const float4 vc = *(const float4*)(xp + 8);
        const float4 vd = *(const float4*)(xp + 12);
        float ssq = va.x*va.x + va.y*va.y + va.z*va.z + va.w*va.w
                  + vb.x*vb.x + vb.y*vb.y + vb.z*vb.z + vb.w*vb.w
                  + vc.x*vc.x + vc.y*vc.y + vc.z*vc.z + vc.w*vc.w
                  + vd.x*vd.x + vd.y*vd.y + vd.z*vd.z + vd.w*vd.w;
        ssq += __shfl_xor(ssq, 1);
        const float inv = 1.0f / (sqrtf(ssq) + NORM_EPS);
        float fr[16];
        fr[0]=va.x*inv;  fr[1]=va.y*inv;  fr[2]=va.z*inv;  fr[3]=va.w*inv;
        fr[4]=vb.x*inv;  fr[5]=vb.y*inv;  fr[6]=vb.z*inv;  fr[7]=vb.w*inv;
        fr[8]=vc.x*inv;  fr[9]=vc.y*inv;  fr[10]=vc.z*inv; fr[11]=vc.w*inv;
        fr[12]=vd.x*inv; fr[13]=vd.y*inv; fr[14]=vd.z*inv; fr[15]=vd.w*inv;
        const int pg = pw >> 4;
#pragma unroll
        for (int cc = 0; cc < 2; ++cc) {
            const int q = 2 * h + cc;    // k-chunk
            char* dst = wbase + pg * 3072 + (q * 16 + (pw & 15)) * 16;
            s16x8 s0, s1, s2;
#pragma unroll
            for (int i = 0; i < 8; ++i) {
                const Split3 s = split3(fr[cc * 8 + i]);
                s0[i] = s.b0; s1[i] = s.b1; s2[i] = s.b2;
            }
            *(s16x8*)(dst) = s0; *(s16x8*)(dst + 1024) = s1; *(s16x8*)(dst + 2048) = s2;
        }
    }
    __syncthreads();

    // ---- A fragments to registers: 2 point-groups x 3 planes (per wave) ----
    s16x8 A[2][3];
#pragma unroll
    for (int pg = 0; pg < 2; ++pg) {
#pragma unroll
        for (int pl = 0; pl < 3; ++pl)
            A[pg][pl] = *(const s16x8*)(wbase + pg * 3072 + pl * 1024 + lane * 16);
    }

    float bestS[2][4], bestC[2][4];
#pragma unroll
    for (int pg = 0; pg < 2; ++pg)
#pragma unroll
        for (int r = 0; r < 4; ++r) { bestS[pg][r] = -1e30f; bestC[pg][r] = 0.f; }

    const int NT = K >> 4;               // 256 tiles
    const int HT = NT >> 3;              // 32 tiles per team
    const int t0 = team * HT;
    const char* gp  = (const char*)bfrag + (size_t)t0 * 3136 + lane * 16;
    const char* gpe = (const char*)bfrag + (size_t)t0 * 3136 + 3072 + (size_t)col * 4;

    auto compute = [&](const Btile& T, float codef) {
        const f32x4_t initX = {T.ne2, T.ne2, T.ne2, T.ne2};   // -|en|^2 folded into C
#pragma unroll
        for (int pg = 0; pg < 2; ++pg) {
            // 6 split products in ONE accumulator chain (C-in carries sum)
            f32x4_t X = __builtin_amdgcn_mfma_f32_16x16x32_bf16(A[pg][0], T.b0, initX, 0, 0, 0);
            X = __builtin_amdgcn_mfma_f32_16x16x32_bf16(A[pg][0], T.b1, X, 0, 0, 0);
            X = __builtin_amdgcn_mfma_f32_16x16x32_bf16(A[pg][1], T.b1, X, 0, 0, 0);
            X = __builtin_amdgcn_mfma_f32_16x16x32_bf16(A[pg][1], T.b0, X, 0, 0, 0);
            X = __builtin_amdgcn_mfma_f32_16x16x32_bf16(A[pg][0], T.b2, X, 0, 0, 0);
            X = __builtin_amdgcn_mfma_f32_16x16x32_bf16(A[pg][2], T.b0, X, 0, 0, 0);
#pragma unroll
            for (int r = 0; r < 4; ++r) {
                const float sc = X[r];
                if (sc > bestS[pg][r]) { bestS[pg][r] = sc; bestC[pg][r] = codef; }
            }
        }
    };

    auto loadB = [&](const char* base, const char* ebase, Btile& T) {
        T.b0  = *(const s16x8*)(base);
        T.b1  = *(const s16x8*)(base + 1024);
        T.b2  = *(const s16x8*)(base + 2048);
        T.ne2 = *(const float*)(ebase);
    };

    // prologue: this team's tiles t0, t0+1 into the two register buffers
    Btile U, V;
    loadB(gp,        gpe,        U);
    loadB(gp + 3136, gpe + 3136, V);

    float cb = (float)(t0 * 16 + col);   // running code index (exact in fp32)
    for (int t = 0; t < HT; t += 2) {
        // trailing refills overread <=2 tiles past the team range; bytes are
        // valid codebook data or workspace (packed) -- reads only.
        compute(U, cb);
        loadB(gp + 2 * 3136, gpe + 2 * 3136, U);
        compute(V, cb + 16.0f);
        loadB(gp + 3 * 3136, gpe + 3 * 3136, V);
        gp += 6272; gpe += 6272;
        cb += 32.0f;
        // convoy barrier every 8 tiles keeps the 8 waves' streams L1-coherent
        if ((t & 7) == 6) __syncthreads();
    }

    // ---- per-wave argmax across the 16 code-lanes; first-max tie-break ----
#pragma unroll
    for (int pg = 0; pg < 2; ++pg)
#pragma unroll
        for (int r = 0; r < 4; ++r) {
            float s = bestS[pg][r], c = bestC[pg][r];
#pragma unroll
            for (int off = 8; off >= 1; off >>= 1) {
                const float os = __shfl_xor(s, off);
                const float oc = __shfl_xor(c, off);
                if (os > s || (os == s && oc < c)) { s = os; c = oc; }
            }
            if (col == 0) {
                const int p = pg * 16 + (lane >> 4) * 4 + r;   // C/D row map
                const int gpt = n0 + w * 32 + p;
                const unsigned int su = __float_as_uint(s);
                const unsigned int ord = (su >> 31) ? ~su : (su | 0x80000000u);
                const unsigned long long pk =
                    ((unsigned long long)ord << 32) | (unsigned int)(~(unsigned int)(int)c);
                atomicMax(&packed[gpt], pk);
            }
        }

    // ---- last-of-8 team blocks performs the scatter for these 256 points ----
    __threadfence();
    __syncthreads();
    if (tid == 0) lastflag = (atomicAdd(&cnt[bid >> 3], 1u) == 7u);
    __syncthreads();
    if (!lastflag) return;
    __threadfence();

    {
        const int p = n0 + (tid >> 1);   // 2 threads per point, 16 dims each
        const int h = tid & 1;
        const float* xp = &x[(size_t)p * D + h * 16];
        const float4 va = *(const float4*)(xp);
        const float4 vb = *(const float4*)(xp + 4);
        const float4 vc = *(const float4*)(xp + 8);
        const float4 vd = *(const float4*)(xp + 12);
        float ssq = va.x*va.x + va.y*va.y + va.z*va.z + va.w*va.w
                  + vb.x*vb.x + vb.y*vb.y + vb.z*vb.z + vb.w*vb.w
                  + vc.x*vc.x + vc.y*vc.y + vc.z*vc.z + vc.w*vc.w
                  + vd.x*vd.x + vd.y*vd.y + vd.z*vd.z + vd.w*vd.w;
        ssq += __shfl_xor(ssq, 1);
        const float inv = 1.0f / (sqrtf(ssq) + NORM_EPS);
        float fn[16];
        fn[0]=va.x*inv;  fn[1]=va.y*inv;  fn[2]=va.z*inv;  fn[3]=va.w*inv;
        fn[4]=vb.x*inv;  fn[5]=vb.y*inv;  fn[6]=vb.z*inv;  fn[7]=vb.w*inv;
        fn[8]=vc.x*inv;  fn[9]=vc.y*inv;  fn[10]=vc.z*inv; fn[11]=vc.w*inv;
        fn[12]=vd.x*inv; fn[13]=vd.y*inv; fn[14]=vd.z*inv; fn[15]=vd.w*inv;

        const unsigned long long pk =
            *(const volatile unsigned long long*)&packed[p];
        const int b = (int)(~(unsigned int)(pk & 0xFFFFFFFFull));
        if (h == 0) {
            out_ind[p] = (float)b;
            atomicAdd(&bins[b], 1.0f);
        }
#pragma unroll
        for (int i = 0; i < 16; ++i)
            atomicAdd(&o_avg[(size_t)b * D + h * 16 + i], fn[i] * OMD);

        // quantize gather (exact en = 0.5*(b0+b1+b2)); h covers k-chunks 2h,2h+1
        const char* bp = (const char*)bfrag + (size_t)(b >> 4) * 3136;
#pragma unroll
        for (int cc = 0; cc < 2; ++cc) {
            const int q = 2 * h + cc;
            const int lid = q * 16 + (b & 15);
            const s16x8 s0 = *(const s16x8*)(bp +    0 + lid * 16);
            const s16x8 s1 = *(const s16x8*)(bp + 1024 + lid * 16);
            const s16x8 s2 = *(const s16x8*)(bp + 2048 + lid * 16);
            float o[8];
#pragma unroll
            for (int i = 0; i < 8; ++i)
                o[i] = 0.5f * ((bf2f(s0[i]) + bf2f(s1[i])) + bf2f(s2[i]));   // exact
            float4 q0 = {o[0], o[1], o[2], o[3]};
            float4 q1 = {o[4], o[5], o[6], o[7]};
            *(float4*)&out_quant[(size_t)p * D + q * 8]     = q0;
            *(float4*)&out_quant[(size_t)p * D + q * 8 + 4] = q1;
        }
    }
}

// ---------------- K3: cluster_size_new + n_total reduce ----------------
__global__ void reduce_kernel(const float* __restrict__ cluster_size,
                              const float* __restrict__ bins,
                              float* __restrict__ out_cs,
                              float* __restrict__ n_total, int K) {
    __shared__ float red[256];
    float s = 0.f;
    for (int k = threadIdx.x; k < K; k += 256) {
        const float v = cluster_size[k] * DECAY + bins[k] * OMD;
        out_cs[k] = v;
        s += v;
    }
    red[threadIdx.x] = s;
    __syncthreads();
    for (int off = 128; off > 0; off >>= 1) {
        if (threadIdx.x < off) red[threadIdx.x] += red[threadIdx.x + off];
        __syncthreads();
    }
    if (threadIdx.x == 0) n_total[0] = red[0];
}

// ---------------- K4: embed_updated = o_avg / smoothed ----------------
__global__ void upd_kernel(const float* __restrict__ o_avg,
                           const float* __restrict__ out_cs,
                           const float* __restrict__ n_total,
                           float* __restrict__ o_upd, int K) {
    const int i = blockIdx.x * blockDim.x + threadIdx.x;
    if (i >= K * D) return;
    const int k = i >> 5;   // D = 32
    const float nt = n_total[0];
    const float cs = out_cs[k];
    const float sm = (cs + EPS) / (nt + (float)K * EPS) * nt;
    o_upd[i] = o_avg[i] / sm;
}

extern "C" void kernel_launch(void* const* d_in, const int* in_sizes, int n_in,
                              void* d_out, int out_size, void* d_ws, size_t ws_size,
                              hipStream_t stream) {
    const float* x            = (const float*)d_in[0];
    const float* embed        = (const float*)d_in[1];
    const float* cluster_size = (const float*)d_in[2];
    const float* embed_avg    = (const float*)d_in[3];

    const int KD = in_sizes[1];       // K*D = 131072
    const int K  = in_sizes[2];       // 4096
    const int N  = in_sizes[0] / D;   // 65536

    float* ws = (float*)d_ws;
    unsigned short* bfrag = (unsigned short*)ws;     // (K/16) tiles x 3136 B = K*49 floats
    unsigned long long* packed = (unsigned long long*)(ws + (size_t)K * 49);  // N u64
    float* bins = (float*)((char*)packed + (size_t)N * 8);   // K
    float* ntot = bins + K;                                  // 1
    unsigned int* cnt = (unsigned int*)(ntot + 1);           // N/256

    float* out     = (float*)d_out;
    float* o_quant = out;                        // N*D
    float* o_ind   = o_quant + (size_t)N * D;    // N
    float* o_cs    = o_ind   + N;                // K
    float* o_avg   = o_cs    + K;                // KD
    float* o_upd   = o_avg   + KD;               // KD

    // zero packed + bins + ntot + cnt (contiguous)
    (void)hipMemsetAsync(packed, 0,
        (size_t)N * 8 + ((size_t)K + 1 + (size_t)N / 256) * sizeof(unsigned int), stream);

    prep_codebook<<<(K + 63) / 64, 64, 0, stream>>>(embed, embed_avg, bfrag, o_avg, K);
    assign_kernel<<<(N / 256) * 8, 512, 0, stream>>>(x, bfrag, packed, cnt,
                                                     o_quant, o_ind, bins, o_avg, N, K);
    reduce_kernel<<<1, 256, 0, stream>>>(cluster_size, bins, o_cs, ntot, K);
    upd_kernel<<<(KD + 255) / 256, 256, 0, stream>>>(o_avg, o_cs, ntot, o_upd, K);
}

// Round 18
// 248.750 us; speedup vs baseline: 2.7655x; 2.7655x over previous
//
#include <hip/hip_runtime.h>
#include <float.h>

#define DECAY 0.1f
#define OMD   0.9f
#define EPS   1e-5f
#define NORM_EPS 1e-8f

static constexpr int D = 32;

typedef __attribute__((ext_vector_type(8))) short s16x8;
typedef __attribute__((ext_vector_type(4))) float f32x4_t;

__device__ __forceinline__ float bf2f(short s) {
    return __uint_as_float(((unsigned int)(unsigned short)s) << 16);
}

struct Split3 { short b0, b1, b2; };

// Exact 3-way bf16 truncation split: v == b0 + b1 + b2 (fp32 mantissa = 24 bits = 3x8).
__device__ __forceinline__ Split3 split3(float v) {
    const unsigned int u0 = __float_as_uint(v) & 0xFFFF0000u;
    const float r  = v - __uint_as_float(u0);
    const unsigned int u1 = __float_as_uint(r) & 0xFFFF0000u;
    const float r2 = r - __uint_as_float(u1);
    Split3 s;
    s.b0 = (short)(u0 >> 16);
    s.b1 = (short)(u1 >> 16);
    s.b2 = (short)(__float_as_uint(r2) >> 16);
    return s;
}

// ---------------- K1: normalize codebook + pack MFMA B-tiles + seed o_avg ---
__global__ void prep_codebook(const float* __restrict__ embed,
                              const float* __restrict__ embed_avg,
                              unsigned short* __restrict__ bfrag,
                              float* __restrict__ o_avg,
                              int K) {
    const int k = blockIdx.x * blockDim.x + threadIdx.x;
    if (k >= K) return;
    float v[D]; float ssq = 0.f;
#pragma unroll
    for (int d = 0; d < D; ++d) { v[d] = embed[(size_t)k * D + d]; ssq += v[d] * v[d]; }
    const float inv = 1.0f / (sqrtf(ssq) + NORM_EPS);
    float e2 = 0.f;
    short p0[D], p1[D], p2[D];
#pragma unroll
    for (int d = 0; d < D; ++d) {
        const float e = v[d] * inv;
        e2 += e * e;
        const Split3 s = split3(2.0f * e);   // fold the *2 into the splits (exact)
        p0[d] = s.b0; p1[d] = s.b1; p2[d] = s.b2;
    }
    char* base = (char*)bfrag + (size_t)(k >> 4) * 3136;   // tile base, bytes
    const int col = k & 15;
    *(float*)(base + 3072 + col * 4) = -e2;
#pragma unroll
    for (int g = 0; g < 4; ++g) {                 // k-chunk g -> lane g*16+col
        const int lid = g * 16 + col;
        s16x8 s0, s1, s2;
#pragma unroll
        for (int i = 0; i < 8; ++i) { s0[i] = p0[g*8+i]; s1[i] = p1[g*8+i]; s2[i] = p2[g*8+i]; }
        *(s16x8*)(base +    0 + lid * 16) = s0;
        *(s16x8*)(base + 1024 + lid * 16) = s1;
        *(s16x8*)(base + 2048 + lid * 16) = s2;
    }
#pragma unroll
    for (int d = 0; d < D; ++d)
        o_avg[(size_t)k * D + d] = embed_avg[(size_t)k * D + d] * DECAY;
}

// B tile held entirely in registers (13 VGPRs).
struct Btile { s16x8 b0, b1, b2; float ne2; };

// ---------------- K2: MFMA assignment + fused last-block scatter ------------
// R17 minus __threadfence (the L2-flush disaster). Release = __syncthreads'
// vmcnt(0) drain of the device-scope atomicMax ops; acquire = agent-scope
// __hip_atomic_load of packed (bypasses stale L1/L2 copies). No L2 flush.
__global__ __launch_bounds__(512)
void assign_kernel(const float* __restrict__ x,
                   const unsigned short* __restrict__ bfrag,
                   unsigned long long* __restrict__ packed,
                   unsigned int* __restrict__ cnt,
                   float* __restrict__ out_quant,
                   float* __restrict__ out_ind,
                   float* __restrict__ bins,
                   float* __restrict__ o_avg,
                   int N, int K) {
    __shared__ char sm[49152];           // 8 waves x 6144 B A-fragment exchange
    __shared__ int  lastflag;

    const int tid  = threadIdx.x;
    const int lane = tid & 63;
    const int w    = tid >> 6;
    const int bid  = blockIdx.x;
    const int team = bid & 7;
    const int n0   = (bid >> 3) * 256;   // block's first point
    const int col  = lane & 15;
    char* wbase = &sm[w * 6144];

    // ---- phase 1: per-wave 32 points, 2 lanes/pt x 16 floats ----
    {
        const int pw = lane >> 1, h = lane & 1;
        const float* xp = &x[(size_t)(n0 + w * 32 + pw) * D + h * 16];
        const float4 va = *(const float4*)(xp);
        const float4 vb = *(const float4*)(xp + 4);
        const float4 vc = *(const float4*)(xp + 8);
        const float4 vd = *(const float4*)(xp + 12);
        float ssq = va.x*va.x + va.y*va.y + va.z*va.z + va.w*va.w
                  + vb.x*vb.x + vb.y*vb.y + vb.z*vb.z + vb.w*vb.w
                  + vc.x*vc.x + vc.y*vc.y + vc.z*vc.z + vc.w*vc.w
                  + vd.x*vd.x + vd.y*vd.y + vd.z*vd.z + vd.w*vd.w;
        ssq += __shfl_xor(ssq, 1);
        const float inv = 1.0f / (sqrtf(ssq) + NORM_EPS);
        float fr[16];
        fr[0]=va.x*inv;  fr[1]=va.y*inv;  fr[2]=va.z*inv;  fr[3]=va.w*inv;
        fr[4]=vb.x*inv;  fr[5]=vb.y*inv;  fr[6]=vb.z*inv;  fr[7]=vb.w*inv;
        fr[8]=vc.x*inv;  fr[9]=vc.y*inv;  fr[10]=vc.z*inv; fr[11]=vc.w*inv;
        fr[12]=vd.x*inv; fr[13]=vd.y*inv; fr[14]=vd.z*inv; fr[15]=vd.w*inv;
        const int pg = pw >> 4;
#pragma unroll
        for (int cc = 0; cc < 2; ++cc) {
            const int q = 2 * h + cc;    // k-chunk
            char* dst = wbase + pg * 3072 + (q * 16 + (pw & 15)) * 16;
            s16x8 s0, s1, s2;
#pragma unroll
            for (int i = 0; i < 8; ++i) {
                const Split3 s = split3(fr[cc * 8 + i]);
                s0[i] = s.b0; s1[i] = s.b1; s2[i] = s.b2;
            }
            *(s16x8*)(dst) = s0; *(s16x8*)(dst + 1024) = s1; *(s16x8*)(dst + 2048) = s2;
        }
    }
    __syncthreads();

    // ---- A fragments to registers: 2 point-groups x 3 planes (per wave) ----
    s16x8 A[2][3];
#pragma unroll
    for (int pg = 0; pg < 2; ++pg) {
#pragma unroll
        for (int pl = 0; pl < 3; ++pl)
            A[pg][pl] = *(const s16x8*)(wbase + pg * 3072 + pl * 1024 + lane * 16);
    }

    float bestS[2][4], bestC[2][4];
#pragma unroll
    for (int pg = 0; pg < 2; ++pg)
#pragma unroll
        for (int r = 0; r < 4; ++r) { bestS[pg][r] = -1e30f; bestC[pg][r] = 0.f; }

    const int NT = K >> 4;               // 256 tiles
    const int HT = NT >> 3;              // 32 tiles per team
    const int t0 = team * HT;
    const char* gp  = (const char*)bfrag + (size_t)t0 * 3136 + lane * 16;
    const char* gpe = (const char*)bfrag + (size_t)t0 * 3136 + 3072 + (size_t)col * 4;

    auto compute = [&](const Btile& T, float codef) {
        const f32x4_t initX = {T.ne2, T.ne2, T.ne2, T.ne2};   // -|en|^2 folded into C
#pragma unroll
        for (int pg = 0; pg < 2; ++pg) {
            // 6 split products in ONE accumulator chain (C-in carries sum)
            f32x4_t X = __builtin_amdgcn_mfma_f32_16x16x32_bf16(A[pg][0], T.b0, initX, 0, 0, 0);
            X = __builtin_amdgcn_mfma_f32_16x16x32_bf16(A[pg][0], T.b1, X, 0, 0, 0);
            X = __builtin_amdgcn_mfma_f32_16x16x32_bf16(A[pg][1], T.b1, X, 0, 0, 0);
            X = __builtin_amdgcn_mfma_f32_16x16x32_bf16(A[pg][1], T.b0, X, 0, 0, 0);
            X = __builtin_amdgcn_mfma_f32_16x16x32_bf16(A[pg][0], T.b2, X, 0, 0, 0);
            X = __builtin_amdgcn_mfma_f32_16x16x32_bf16(A[pg][2], T.b0, X, 0, 0, 0);
#pragma unroll
            for (int r = 0; r < 4; ++r) {
                const float sc = X[r];
                if (sc > bestS[pg][r]) { bestS[pg][r] = sc; bestC[pg][r] = codef; }
            }
        }
    };

    auto loadB = [&](const char* base, const char* ebase, Btile& T) {
        T.b0  = *(const s16x8*)(base);
        T.b1  = *(const s16x8*)(base + 1024);
        T.b2  = *(const s16x8*)(base + 2048);
        T.ne2 = *(const float*)(ebase);
    };

    // prologue: this team's tiles t0, t0+1 into the two register buffers
    Btile U, V;
    loadB(gp,        gpe,        U);
    loadB(gp + 3136, gpe + 3136, V);

    float cb = (float)(t0 * 16 + col);   // running code index (exact in fp32)
    for (int t = 0; t < HT; t += 2) {
        // trailing refills overread <=2 tiles past the team range; bytes are
        // valid codebook data or workspace (packed) -- reads only.
        compute(U, cb);
        loadB(gp + 2 * 3136, gpe + 2 * 3136, U);
        compute(V, cb + 16.0f);
        loadB(gp + 3 * 3136, gpe + 3 * 3136, V);
        gp += 6272; gpe += 6272;
        cb += 32.0f;
        // convoy barrier every 8 tiles keeps the 8 waves' streams L1-coherent
        if ((t & 7) == 6) __syncthreads();
    }

    // ---- per-wave argmax across the 16 code-lanes; first-max tie-break ----
#pragma unroll
    for (int pg = 0; pg < 2; ++pg)
#pragma unroll
        for (int r = 0; r < 4; ++r) {
            float s = bestS[pg][r], c = bestC[pg][r];
#pragma unroll
            for (int off = 8; off >= 1; off >>= 1) {
                const float os = __shfl_xor(s, off);
                const float oc = __shfl_xor(c, off);
                if (os > s || (os == s && oc < c)) { s = os; c = oc; }
            }
            if (col == 0) {
                const int p = pg * 16 + (lane >> 4) * 4 + r;   // C/D row map
                const int gpt = n0 + w * 32 + p;
                const unsigned int su = __float_as_uint(s);
                const unsigned int ord = (su >> 31) ? ~su : (su | 0x80000000u);
                const unsigned long long pk =
                    ((unsigned long long)ord << 32) | (unsigned int)(~(unsigned int)(int)c);
                atomicMax(&packed[gpt], pk);   // device-scope, coherent point
            }
        }

    // ---- last-of-8 team blocks performs the scatter for these 256 points ----
    // __syncthreads drains vmcnt(0): all this block's atomicMax ops have
    // performed at the coherent point before the counter increment (release).
    __syncthreads();
    if (tid == 0) {
        const unsigned int prev = __hip_atomic_fetch_add(
            &cnt[bid >> 3], 1u, __ATOMIC_RELAXED, __HIP_MEMORY_SCOPE_AGENT);
        lastflag = (prev == 7u);
    }
    __syncthreads();
    if (!lastflag) return;

    {
        const int p = n0 + (tid >> 1);   // 2 threads per point, 16 dims each
        const int h = tid & 1;
        const float* xp = &x[(size_t)p * D + h * 16];
        const float4 va = *(const float4*)(xp);
        const float4 vb = *(const float4*)(xp + 4);
        const float4 vc = *(const float4*)(xp + 8);
        const float4 vd = *(const float4*)(xp + 12);
        float ssq = va.x*va.x + va.y*va.y + va.z*va.z + va.w*va.w
                  + vb.x*vb.x + vb.y*vb.y + vb.z*vb.z + vb.w*vb.w
                  + vc.x*vc.x + vc.y*vc.y + vc.z*vc.z + vc.w*vc.w
                  + vd.x*vd.x + vd.y*vd.y + vd.z*vd.z + vd.w*vd.w;
        ssq += __shfl_xor(ssq, 1);
        const float inv = 1.0f / (sqrtf(ssq) + NORM_EPS);
        float fn[16];
        fn[0]=va.x*inv;  fn[1]=va.y*inv;  fn[2]=va.z*inv;  fn[3]=va.w*inv;
        fn[4]=vb.x*inv;  fn[5]=vb.y*inv;  fn[6]=vb.z*inv;  fn[7]=vb.w*inv;
        fn[8]=vc.x*inv;  fn[9]=vc.y*inv;  fn[10]=vc.z*inv; fn[11]=vc.w*inv;
        fn[12]=vd.x*inv; fn[13]=vd.y*inv; fn[14]=vd.z*inv; fn[15]=vd.w*inv;

        // acquire: agent-scope atomic load bypasses any stale cached copy
        const unsigned long long pk = __hip_atomic_load(
            &packed[p], __ATOMIC_RELAXED, __HIP_MEMORY_SCOPE_AGENT);
        const int b = (int)(~(unsigned int)(pk & 0xFFFFFFFFull));
        if (h == 0) {
            out_ind[p] = (float)b;
            atomicAdd(&bins[b], 1.0f);
        }
#pragma unroll
        for (int i = 0; i < 16; ++i)
            atomicAdd(&o_avg[(size_t)b * D + h * 16 + i], fn[i] * OMD);

        // quantize gather (exact en = 0.5*(b0+b1+b2)); h covers k-chunks 2h,2h+1
        const char* bp = (const char*)bfrag + (size_t)(b >> 4) * 3136;
#pragma unroll
        for (int cc = 0; cc < 2; ++cc) {
            const int q = 2 * h + cc;
            const int lid = q * 16 + (b & 15);
            const s16x8 s0 = *(const s16x8*)(bp +    0 + lid * 16);
            const s16x8 s1 = *(const s16x8*)(bp + 1024 + lid * 16);
            const s16x8 s2 = *(const s16x8*)(bp + 2048 + lid * 16);
            float o[8];
#pragma unroll
            for (int i = 0; i < 8; ++i)
                o[i] = 0.5f * ((bf2f(s0[i]) + bf2f(s1[i])) + bf2f(s2[i]));   // exact
            float4 q0 = {o[0], o[1], o[2], o[3]};
            float4 q1 = {o[4], o[5], o[6], o[7]};
            *(float4*)&out_quant[(size_t)p * D + q * 8]     = q0;
            *(float4*)&out_quant[(size_t)p * D + q * 8 + 4] = q1;
        }
    }
}

// ---------------- K3: cluster_size_new + n_total reduce ----------------
__global__ void reduce_kernel(const float* __restrict__ cluster_size,
                              const float* __restrict__ bins,
                              float* __restrict__ out_cs,
                              float* __restrict__ n_total, int K) {
    __shared__ float red[256];
    float s = 0.f;
    for (int k = threadIdx.x; k < K; k += 256) {
        const float v = cluster_size[k] * DECAY + bins[k] * OMD;
        out_cs[k] = v;
        s += v;
    }
    red[threadIdx.x] = s;
    __syncthreads();
    for (int off = 128; off > 0; off >>= 1) {
        if (threadIdx.x < off) red[threadIdx.x] += red[threadIdx.x + off];
        __syncthreads();
    }
    if (threadIdx.x == 0) n_total[0] = red[0];
}

// ---------------- K4: embed_updated = o_avg / smoothed ----------------
__global__ void upd_kernel(const float* __restrict__ o_avg,
                           const float* __restrict__ out_cs,
                           const float* __restrict__ n_total,
                           float* __restrict__ o_upd, int K) {
    const int i = blockIdx.x * blockDim.x + threadIdx.x;
    if (i >= K * D) return;
    const int k = i >> 5;   // D = 32
    const float nt = n_total[0];
    const float cs = out_cs[k];
    const float sm = (cs + EPS) / (nt + (float)K * EPS) * nt;
    o_upd[i] = o_avg[i] / sm;
}

extern "C" void kernel_launch(void* const* d_in, const int* in_sizes, int n_in,
                              void* d_out, int out_size, void* d_ws, size_t ws_size,
                              hipStream_t stream) {
    const float* x            = (const float*)d_in[0];
    const float* embed        = (const float*)d_in[1];
    const float* cluster_size = (const float*)d_in[2];
    const float* embed_avg    = (const float*)d_in[3];

    const int KD = in_sizes[1];       // K*D = 131072
    const int K  = in_sizes[2];       // 4096
    const int N  = in_sizes[0] / D;   // 65536

    float* ws = (float*)d_ws;
    unsigned short* bfrag = (unsigned short*)ws;     // (K/16) tiles x 3136 B = K*49 floats
    unsigned long long* packed = (unsigned long long*)(ws + (size_t)K * 49);  // N u64
    float* bins = (float*)((char*)packed + (size_t)N * 8);   // K
    float* ntot = bins + K;                                  // 1
    unsigned int* cnt = (unsigned int*)(ntot + 1);           // N/256

    float* out     = (float*)d_out;
    float* o_quant = out;                        // N*D
    float* o_ind   = o_quant + (size_t)N * D;    // N
    float* o_cs    = o_ind   + N;                // K
    float* o_avg   = o_cs    + K;                // KD
    float* o_upd   = o_avg   + KD;               // KD

    // zero packed + bins + ntot + cnt (contiguous)
    (void)hipMemsetAsync(packed, 0,
        (size_t)N * 8 + ((size_t)K + 1 + (size_t)N / 256) * sizeof(unsigned int), stream);

    prep_codebook<<<(K + 63) / 64, 64, 0, stream>>>(embed, embed_avg, bfrag, o_avg, K);
    assign_kernel<<<(N / 256) * 8, 512, 0, stream>>>(x, bfrag, packed, cnt,
                                                     o_quant, o_ind, bins, o_avg, N, K);
    reduce_kernel<<<1, 256, 0, stream>>>(cluster_size, bins, o_cs, ntot, K);
    upd_kernel<<<(KD + 255) / 256, 256, 0, stream>>>(o_avg, o_cs, ntot, o_upd, K);
}

// Round 19
// 156.026 us; speedup vs baseline: 4.4090x; 1.5943x over previous
//
#include <hip/hip_runtime.h>
#include <float.h>

#define DECAY 0.1f
#define OMD   0.9f
#define EPS   1e-5f
#define NORM_EPS 1e-8f

static constexpr int D = 32;

typedef __attribute__((ext_vector_type(8))) short s16x8;
typedef __attribute__((ext_vector_type(4))) float f32x4_t;

__device__ __forceinline__ float bf2f(short s) {
    return __uint_as_float(((unsigned int)(unsigned short)s) << 16);
}

struct Split3 { short b0, b1, b2; };

// Exact 3-way bf16 truncation split: v == b0 + b1 + b2 (fp32 mantissa = 24 bits = 3x8).
__device__ __forceinline__ Split3 split3(float v) {
    const unsigned int u0 = __float_as_uint(v) & 0xFFFF0000u;
    const float r  = v - __uint_as_float(u0);
    const unsigned int u1 = __float_as_uint(r) & 0xFFFF0000u;
    const float r2 = r - __uint_as_float(u1);
    Split3 s;
    s.b0 = (short)(u0 >> 16);
    s.b1 = (short)(u1 >> 16);
    s.b2 = (short)(__float_as_uint(r2) >> 16);
    return s;
}

// ---------------- K1: normalize codebook + pack MFMA B-tiles ----------------
// Per 16-code tile (3136 B global): 3 planes x 1024 B of bf16 B-fragments, then
// 16 floats of -|en|^2 (64 B). Lane l's fragment of plane p is the contiguous
// 16 B at tile_base + p*1024 + l*16 -> direct global_load_dwordx4 to VGPRs.
// B[k][col] = 2*en[tile*16+col][k]; lane l holds k-chunk l>>4, col l&15.
__global__ void prep_codebook(const float* __restrict__ embed,
                              unsigned short* __restrict__ bfrag,
                              int K) {
    const int k = blockIdx.x * blockDim.x + threadIdx.x;
    if (k >= K) return;
    float v[D]; float ssq = 0.f;
#pragma unroll
    for (int d = 0; d < D; ++d) { v[d] = embed[(size_t)k * D + d]; ssq += v[d] * v[d]; }
    const float inv = 1.0f / (sqrtf(ssq) + NORM_EPS);
    float e2 = 0.f;
    short p0[D], p1[D], p2[D];
#pragma unroll
    for (int d = 0; d < D; ++d) {
        const float e = v[d] * inv;
        e2 += e * e;
        const Split3 s = split3(2.0f * e);   // fold the *2 into the splits (exact)
        p0[d] = s.b0; p1[d] = s.b1; p2[d] = s.b2;
    }
    char* base = (char*)bfrag + (size_t)(k >> 4) * 3136;   // tile base, bytes
    const int col = k & 15;
    *(float*)(base + 3072 + col * 4) = -e2;
#pragma unroll
    for (int g = 0; g < 4; ++g) {                 // k-chunk g -> lane g*16+col
        const int lid = g * 16 + col;
        s16x8 s0, s1, s2;
#pragma unroll
        for (int i = 0; i < 8; ++i) { s0[i] = p0[g*8+i]; s1[i] = p1[g*8+i]; s2[i] = p2[g*8+i]; }
        *(s16x8*)(base +    0 + lid * 16) = s0;
        *(s16x8*)(base + 1024 + lid * 16) = s1;
        *(s16x8*)(base + 2048 + lid * 16) = s2;
    }
}

// B tile held entirely in registers (13 VGPRs).
struct Btile { s16x8 b0, b1, b2; float ne2; };

// ------- K2: MFMA assignment, 2 teams x 4-wave convoy, inline scatter -------
// 512 thr = 8 waves, 128 points/block, grid = N/128 = 512 (4 blocks/CU, 32
// waves/CU). Teams: waves 0-3 = codes [0,K/2) in convoy (same tiles, 4-way
// L1 sharing); waves 4-7 = [K/2,K). Each wave owns 32 points (2 pg), per-tile
// math bit-identical to R15 (6-product single chain). Intra-block 2-way
// combine + R15's inline scatter (every block scatters its own points ->
// naturally overlapped across blocks; no global sync, no fences).
__global__ __launch_bounds__(512)
void assign_kernel(const float* __restrict__ x,
                   const unsigned short* __restrict__ bfrag,
                   float* __restrict__ out_quant,
                   float* __restrict__ out_ind,
                   float* __restrict__ bins,
                   float* __restrict__ esum,
                   int N, int K) {
    constexpr int PB = 128;
    __shared__ char  sm[24576];          // 8 point-groups x 3072 B A-fragments
    __shared__ float teamS[2][PB];
    __shared__ float teamC[2][PB];
    __shared__ int   best_c[PB];

    const int tid  = threadIdx.x;
    const int lane = tid & 63;
    const int w    = tid >> 6;           // wave 0..7
    const int team = w >> 2;             // 0: codes [0,K/2), 1: [K/2,K)
    const int slot = w & 3;              // 4 waves per team -> point quarter
    const int n0   = blockIdx.x * PB;
    const int col  = lane & 15;

    float fn_r[8];
    // ---- phase 1: load + normalize + exact split into A-fragment LDS ----
    // 4 threads per point, 8 floats each (all 512 threads active).
    {
        const int p = tid >> 2, q = tid & 3;
        const float* xp = &x[(size_t)(n0 + p) * D + q * 8];
        const float4 va = *(const float4*)(xp);
        const float4 vb = *(const float4*)(xp + 4);
        float ssq = va.x*va.x + va.y*va.y + va.z*va.z + va.w*va.w
                  + vb.x*vb.x + vb.y*vb.y + vb.z*vb.z + vb.w*vb.w;
        ssq += __shfl_xor(ssq, 1);
        ssq += __shfl_xor(ssq, 2);
        const float inv = 1.0f / (sqrtf(ssq) + NORM_EPS);
        fn_r[0]=va.x*inv; fn_r[1]=va.y*inv; fn_r[2]=va.z*inv; fn_r[3]=va.w*inv;
        fn_r[4]=vb.x*inv; fn_r[5]=vb.y*inv; fn_r[6]=vb.z*inv; fn_r[7]=vb.w*inv;
        // A-frag: group g=p>>4, k-chunk q -> lane q*16+(p&15), planes stride 1024B
        char* dst = &sm[(p >> 4) * 3072 + (q * 16 + (p & 15)) * 16];
        s16x8 s0, s1, s2;
#pragma unroll
        for (int i = 0; i < 8; ++i) {
            const Split3 s = split3(fn_r[i]);
            s0[i] = s.b0; s1[i] = s.b1; s2[i] = s.b2;
        }
        *(s16x8*)(dst) = s0; *(s16x8*)(dst + 1024) = s1; *(s16x8*)(dst + 2048) = s2;
    }
    __syncthreads();

    // ---- A fragments to registers: wave's 2 point-groups x 3 planes ----
    // Wave (team, slot) owns points slot*32..slot*32+31 = pg {2*slot, 2*slot+1}.
    // Both teams' same-slot waves read the SAME A-frags.
    s16x8 A[2][3];
#pragma unroll
    for (int pg = 0; pg < 2; ++pg) {
#pragma unroll
        for (int pl = 0; pl < 3; ++pl)
            A[pg][pl] = *(const s16x8*)&sm[(slot * 2 + pg) * 3072 + pl * 1024 + lane * 16];
    }

    float bestS[2][4], bestC[2][4];
#pragma unroll
    for (int pg = 0; pg < 2; ++pg)
#pragma unroll
        for (int r = 0; r < 4; ++r) { bestS[pg][r] = -1e30f; bestC[pg][r] = 0.f; }

    const int NT = K >> 4;               // 256 tiles
    const int HT = NT >> 1;              // 128 tiles per team
    const int t0 = team * HT;            // this team's first tile
    const char* gp  = (const char*)bfrag + (size_t)t0 * 3136 + lane * 16;
    const char* gpe = (const char*)bfrag + (size_t)t0 * 3136 + 3072 + (size_t)col * 4;

    auto compute = [&](const Btile& T, float codef) {
        const f32x4_t initX = {T.ne2, T.ne2, T.ne2, T.ne2};   // -|en|^2 folded into C
#pragma unroll
        for (int pg = 0; pg < 2; ++pg) {
            // 6 split products in ONE accumulator chain (C-in carries sum).
            f32x4_t X = __builtin_amdgcn_mfma_f32_16x16x32_bf16(A[pg][0], T.b0, initX, 0, 0, 0);
            X = __builtin_amdgcn_mfma_f32_16x16x32_bf16(A[pg][0], T.b1, X, 0, 0, 0);
            X = __builtin_amdgcn_mfma_f32_16x16x32_bf16(A[pg][1], T.b1, X, 0, 0, 0);
            X = __builtin_amdgcn_mfma_f32_16x16x32_bf16(A[pg][1], T.b0, X, 0, 0, 0);
            X = __builtin_amdgcn_mfma_f32_16x16x32_bf16(A[pg][0], T.b2, X, 0, 0, 0);
            X = __builtin_amdgcn_mfma_f32_16x16x32_bf16(A[pg][2], T.b0, X, 0, 0, 0);
#pragma unroll
            for (int r = 0; r < 4; ++r) {
                const float sc = X[r];
                if (sc > bestS[pg][r]) { bestS[pg][r] = sc; bestC[pg][r] = codef; }
            }
        }
    };

    auto loadB = [&](const char* base, const char* ebase, Btile& T) {
        T.b0  = *(const s16x8*)(base);
        T.b1  = *(const s16x8*)(base + 1024);
        T.b2  = *(const s16x8*)(base + 2048);
        T.ne2 = *(const float*)(ebase);
    };

    // prologue: this team's tiles t0, t0+1 into the two register buffers
    Btile U, V;
    loadB(gp,        gpe,        U);
    loadB(gp + 3136, gpe + 3136, V);

    float cb = (float)(t0 * 16 + col);   // running code index (exact in fp32)
    for (int t = 0; t < HT; t += 2) {
        // trailing refills overread <=2 tiles past the team range; bytes are
        // valid codebook data or workspace (bins/esum) -- reads only.
        compute(U, cb);
        loadB(gp + 2 * 3136, gpe + 2 * 3136, U);
        compute(V, cb + 16.0f);
        loadB(gp + 3 * 3136, gpe + 3 * 3136, V);
        gp += 6272; gpe += 6272;
        cb += 32.0f;
        // convoy barrier every 8 tiles keeps each team's 4 waves L1-coherent
        if ((t & 7) == 6) __syncthreads();
    }

    // ---- per-wave argmax across the 16 code-lanes; first-max tie-break ----
#pragma unroll
    for (int pg = 0; pg < 2; ++pg)
#pragma unroll
        for (int r = 0; r < 4; ++r) {
            float s = bestS[pg][r], c = bestC[pg][r];
#pragma unroll
            for (int off = 8; off >= 1; off >>= 1) {
                const float os = __shfl_xor(s, off);
                const float oc = __shfl_xor(c, off);
                if (os > s || (os == s && oc < c)) { s = os; c = oc; }
            }
            if (col == 0) {
                const int p = slot * 32 + pg * 16 + (lane >> 4) * 4 + r;  // C/D row map
                teamS[team][p] = s;
                teamC[team][p] = c;
            }
        }
    __syncthreads();

    // ---- cross-team combine (team1 codes all higher: wins only on strict >) --
    if (tid < PB) {
        const float s0 = teamS[0][tid], s1 = teamS[1][tid];
        const float c  = (s1 > s0) ? teamC[1][tid] : teamC[0][tid];
        out_ind[n0 + tid] = c;
        best_c[tid] = (int)c;
        atomicAdd(&bins[(int)c], 1.0f);
    }
    __syncthreads();

    // ---- quantize gather (exact en = 0.5*(b0+b1+b2)) + embed_sum scatter ----
    {
        const int p = tid >> 2, q = tid & 3;
        const int b = best_c[p];
#pragma unroll
        for (int i = 0; i < 8; ++i)
            atomicAdd(&esum[(size_t)b * D + q * 8 + i], fn_r[i]);
        const char* bp = (const char*)bfrag + (size_t)(b >> 4) * 3136;
        const int lid = q * 16 + (b & 15);
        const s16x8 s0 = *(const s16x8*)(bp +    0 + lid * 16);
        const s16x8 s1 = *(const s16x8*)(bp + 1024 + lid * 16);
        const s16x8 s2 = *(const s16x8*)(bp + 2048 + lid * 16);
        float o[8];
#pragma unroll
        for (int i = 0; i < 8; ++i)
            o[i] = 0.5f * ((bf2f(s0[i]) + bf2f(s1[i])) + bf2f(s2[i]));   // exact
        float4 q0 = {o[0], o[1], o[2], o[3]};
        float4 q1 = {o[4], o[5], o[6], o[7]};
        *(float4*)&out_quant[(size_t)(n0 + p) * D + q * 8]     = q0;
        *(float4*)&out_quant[(size_t)(n0 + p) * D + q * 8 + 4] = q1;
    }
}

// ---------------- K3a: cluster_size_new + n_total reduce ----------------
__global__ void reduce_kernel(const float* __restrict__ cluster_size,
                              const float* __restrict__ bins,
                              float* __restrict__ out_cs,
                              float* __restrict__ n_total, int K) {
    __shared__ float red[256];
    float s = 0.f;
    for (int k = threadIdx.x; k < K; k += 256) {
        const float v = cluster_size[k] * DECAY + bins[k] * OMD;
        out_cs[k] = v;
        s += v;
    }
    red[threadIdx.x] = s;
    __syncthreads();
    for (int off = 128; off > 0; off >>= 1) {
        if (threadIdx.x < off) red[threadIdx.x] += red[threadIdx.x + off];
        __syncthreads();
    }
    if (threadIdx.x == 0) n_total[0] = red[0];
}

// ---------------- K3b: embed_avg_new + embed_updated ----------------
__global__ void finalize_kernel(const float* __restrict__ embed_avg,
                                const float* __restrict__ esum,
                                const float* __restrict__ out_cs,
                                const float* __restrict__ n_total,
                                float* __restrict__ out_avg,
                                float* __restrict__ out_upd,
                                int K) {
    const int i = blockIdx.x * blockDim.x + threadIdx.x;
    if (i >= K * D) return;
    const int k = i >> 5;   // D = 32
    const float avg = embed_avg[i] * DECAY + esum[i] * OMD;
    out_avg[i] = avg;
    const float nt = n_total[0];
    const float cs = out_cs[k];
    const float sm = (cs + EPS) / (nt + (float)K * EPS) * nt;
    out_upd[i] = avg / sm;
}

extern "C" void kernel_launch(void* const* d_in, const int* in_sizes, int n_in,
                              void* d_out, int out_size, void* d_ws, size_t ws_size,
                              hipStream_t stream) {
    const float* x            = (const float*)d_in[0];
    const float* embed        = (const float*)d_in[1];
    const float* cluster_size = (const float*)d_in[2];
    const float* embed_avg    = (const float*)d_in[3];

    const int KD = in_sizes[1];       // K*D = 131072
    const int K  = in_sizes[2];       // 4096
    const int N  = in_sizes[0] / D;   // 65536

    float* ws = (float*)d_ws;
    unsigned short* bfrag = (unsigned short*)ws;     // (K/16) tiles x 3136 B = K*49 floats
    float* bins  = ws + (size_t)K * 49;              // K
    float* esum  = bins + K;                         // KD
    float* ntot  = esum + KD;                        // 1   (total ~1.33 MB)

    float* out     = (float*)d_out;
    float* o_quant = out;                        // N*D
    float* o_ind   = o_quant + (size_t)N * D;    // N
    float* o_cs    = o_ind   + N;                // K
    float* o_avg   = o_cs    + K;                // KD
    float* o_upd   = o_avg   + KD;               // KD

    // zero the accumulators (bins, esum, ntot are contiguous)
    (void)hipMemsetAsync(bins, 0, (size_t)(K + KD + 1) * sizeof(float), stream);

    prep_codebook<<<(K + 63) / 64, 64, 0, stream>>>(embed, bfrag, K);
    assign_kernel<<<N / 128, 512, 0, stream>>>(x, bfrag,
                                               o_quant, o_ind, bins, esum, N, K);
    reduce_kernel<<<1, 256, 0, stream>>>(cluster_size, bins, o_cs, ntot, K);
    finalize_kernel<<<(KD + 255) / 256, 256, 0, stream>>>(embed_avg, esum, o_cs, ntot,
                                                          o_avg, o_upd, K);
}